// Round 20
// baseline (140.913 us; speedup 1.0000x reference)
//
#include <hip/hip_runtime.h>
#include <math.h>

typedef __attribute__((ext_vector_type(2))) float f32x2;
typedef __attribute__((ext_vector_type(4))) float f32x4;

// Problem dims (fixed): (B=4, 1, D=160, H=192, W=192) f32
#define BDIM 4
#define DDIM 160
#define HDIM 192
#define WDIM 192
#define NTOT (BDIM * DDIM * HDIM * WDIM)
#define SLICEPX (HDIM * WDIM)          // 36864

template<int N> struct IC { static constexpr int v = N; };

__device__ __forceinline__ float rcp_fast(float x) {
#if __has_builtin(__builtin_amdgcn_rcpf)
    return __builtin_amdgcn_rcpf(x);
#else
    return 1.0f / x;
#endif
}

// packed pair: {lo16: bf16(lo), hi16: bf16(hi)} in ONE instruction
__device__ __forceinline__ unsigned cvtpk(float lo, float hi) {
    unsigned r;
    asm("v_cvt_pk_bf16_f32 %0, %1, %2" : "=v"(r) : "v"(lo), "v"(hi));
    return r;
}

// unpack bf16 pair -> f32x2 {lo, hi}
__device__ __forceinline__ f32x2 unpk(unsigned u) {
    return (f32x2){__uint_as_float(u << 16), __uint_as_float(u & 0xffff0000u)};
}

#define G7INIT { 0.03663285f, 0.11128076f, 0.21674532f, 0.27068215f, \
                 0.21674532f, 0.11128076f, 0.03663285f }

// LDS-visibility-only barrier: prefetch global loads stay in flight across it.
#define STEP_BARRIER() do {                                   \
    asm volatile("s_waitcnt lgkmcnt(0)" ::: "memory");        \
    __builtin_amdgcn_s_barrier();                             \
} while (0)

// ===================== Kernel A: per-slice H+W blur -> bf16 fields ==========
// s/d basis fields: HW(s), HW(d), HW(s^2), HW(d^2) packed 4 x bf16 (uint2).
// ONE barrier per slice: {issue(c+2) | H(c) | Wstore(c-1) | commit(c+1)}.
// raw bf16-packed parity dbuf (21.5 KB) + hb parity f32 (51.2 KB) = 72.8 KB
// -> 2 blocks/CU (PROVEN regime; (512,4), VGPR ~56, zero spill).
// SPB=8: prologue/epilogue amortized over 8 slices (1.375 barrier-steps/slice
// vs 1.75 at SPB=4); 2016 blocks.
#define ATH 8
#define ARH 14               // ATH + 6
#define HBW 200              // 4 zero-pad cols each side (16B-aligned b128 reads)
#define NSL 166              // buffer slices per batch (by = d+3, d=-3..162)
#define SPB 8                // slices per block
#define NTH 512

struct PFBuf { f32x4 x0, y0, x1, y1; };

__global__ __launch_bounds__(NTH, 4)
void nq_fields(const float* __restrict__ X, const float* __restrict__ Y,
               uint2* __restrict__ F, float2* __restrict__ pl1)
{
    constexpr float Gc[7] = G7INIT;
    __shared__ __align__(16) unsigned rawB[2][ARH][WDIM];  // 21,504 B bf16(s,d)
    __shared__ __align__(16) f32x2 hA[2][ATH][HBW];        // 25,600 B (Hs,Hd)
    __shared__ __align__(16) f32x2 hB[2][ATH][HBW];        // 25,600 B (Hs2,Hd2)
    __shared__ float red[NTH / 64][2];

    const int t = threadIdx.x;
    const int strip = blockIdx.x;                    // 0..23
    const int z = blockIdx.z;                        // batch 0..3
    const int h0 = strip * ATH;
    const int b0 = blockIdx.y * SPB;                 // 0,8,...,160

    // ---- load invariants: two float4 items (672 = 512 + 160) ----
    const int r0 = t / 48, c0 = (t % 48) * 4;
    const int h0r0 = h0 + r0 - 3;
    const bool okh0 = (unsigned)h0r0 < (unsigned)HDIM;
    const bool int0 = (r0 >= 3) && (r0 < 11);
    const int off0 = h0r0 * WDIM + c0;
    const int lof0 = r0 * WDIM + c0;                 // raw flat index

    const bool act1 = t < 160;
    const int i4b = 512 + t;
    const int r1 = i4b / 48, c1 = (i4b % 48) * 4;
    const int h0r1 = h0 + r1 - 3;
    const bool okh1 = act1 && ((unsigned)h0r1 < (unsigned)HDIM);
    const bool int1 = act1 && (r1 >= 3) && (r1 < 11);
    const int off1 = h0r1 * WDIM + c1;
    const int lof1 = r1 * WDIM + c1;

    // ---- H-blur invariants: 2-px items (768 = 512 + 256) ----
    const int hr0 = t / 96,         hw0 = (t % 96) * 2;
    const int hr1 = (t + 512) / 96, hw1 = ((t + 512) % 96) * 2;
    const bool hact1 = t < 256;

    // ---- W-phase invariants: 2-px items (768 = 512 + 256) ----
    const int wr0 = t / 96,         ww0 = (t % 96) * 2;
    const int wr1 = (t + 512) / 96, ww1 = ((t + 512) % 96) * 2;

    // zero pad cols (both parities)
    if (t < 128) {
        const int pp = t >> 6, r = (t >> 3) & 7, c8 = t & 7;
        const int col = (c8 < 4) ? c8 : (192 + c8);
        hA[pp][r][col] = (f32x2){0.f, 0.f};
        hB[pp][r][col] = (f32x2){0.f, 0.f};
    }

    float l1n = 0.f, l1d = 0.f;
    PFBuf pf0, pf1;

    auto validby = [&](int by) { return (by >= 3) && (by < 163); };

    auto issue = [&](PFBuf& p, int by) {             // global loads -> regs
        const int d = by - 3;
        const size_t sbase = ((size_t)z * DDIM + d) * SLICEPX;
        const f32x4 zz = {0.f, 0.f, 0.f, 0.f};
        p.x0 = okh0 ? *(const f32x4*)(X + sbase + off0) : zz;
        p.y0 = okh0 ? *(const f32x4*)(Y + sbase + off0) : zz;
        p.x1 = okh1 ? *(const f32x4*)(X + sbase + off1) : zz;
        p.y1 = okh1 ? *(const f32x4*)(Y + sbase + off1) : zz;
    };

    auto commit = [&](PFBuf& p, int par) {           // L1 + pack s/d -> rawB[par]
        if (int0) {
            #pragma unroll
            for (int j = 0; j < 4; ++j) {
                const float x = p.x0[j], y = p.y0[j];
                const float wgt = (y > -0.9f) ? 5.f : 1.f;
                l1n += wgt * fabsf(x - y);
                l1d += wgt;
            }
        }
        if (int1) {
            #pragma unroll
            for (int j = 0; j < 4; ++j) {
                const float x = p.x1[j], y = p.y1[j];
                const float wgt = (y > -0.9f) ? 5.f : 1.f;
                l1n += wgt * fabsf(x - y);
                l1d += wgt;
            }
        }
        {
            uint4 u;
            u.x = cvtpk(p.x0.x + p.y0.x, p.x0.x - p.y0.x);
            u.y = cvtpk(p.x0.y + p.y0.y, p.x0.y - p.y0.y);
            u.z = cvtpk(p.x0.z + p.y0.z, p.x0.z - p.y0.z);
            u.w = cvtpk(p.x0.w + p.y0.w, p.x0.w - p.y0.w);
            *(uint4*)(&rawB[par][0][0] + lof0) = u;
        }
        if (act1) {
            uint4 u;
            u.x = cvtpk(p.x1.x + p.y1.x, p.x1.x - p.y1.x);
            u.y = cvtpk(p.x1.y + p.y1.y, p.x1.y - p.y1.y);
            u.z = cvtpk(p.x1.z + p.y1.z, p.x1.z - p.y1.z);
            u.w = cvtpk(p.x1.w + p.y1.w, p.x1.w - p.y1.w);
            *(uint4*)(&rawB[par][0][0] + lof1) = u;
        }
    };

    auto hitem = [&](int par, int r, int w0) {       // 2-px H-blur from bf16 raw
        f32x2 aA0 = {0.f, 0.f}, aA1 = {0.f, 0.f};
        f32x2 aB0 = {0.f, 0.f}, aB1 = {0.f, 0.f};
        #pragma unroll
        for (int k = 0; k < 7; ++k) {
            const uint2 u = *(const uint2*)(&rawB[par][r + k][w0]);
            const f32x2 p0 = unpk(u.x);
            const f32x2 p1 = unpk(u.y);
            const float g = Gc[k];
            aA0 += g * p0; aB0 += (g * p0) * p0;
            aA1 += g * p1; aB1 += (g * p1) * p1;
        }
        *(f32x4*)(&hA[par][r][4 + w0]) = (f32x4){aA0.x, aA0.y, aA1.x, aA1.y};
        *(f32x4*)(&hB[par][r][4 + w0]) = (f32x4){aB0.x, aB0.y, aB1.x, aB1.y};
    };

    auto witem = [&](int hp, int r, int w0, size_t obase) {
        f32x2 vA[10], vB[10];
        #pragma unroll
        for (int j = 0; j < 5; ++j) {
            const f32x4 qa = *(const f32x4*)(&hA[hp][r][w0 + 2 * j]);
            vA[2 * j] = (f32x2){qa.x, qa.y}; vA[2 * j + 1] = (f32x2){qa.z, qa.w};
            const f32x4 qb = *(const f32x4*)(&hB[hp][r][w0 + 2 * j]);
            vB[2 * j] = (f32x2){qb.x, qb.y}; vB[2 * j + 1] = (f32x2){qb.z, qb.w};
        }
        f32x2 a0 = {0.f, 0.f}, a1 = {0.f, 0.f};
        f32x2 e0 = {0.f, 0.f}, e1 = {0.f, 0.f};
        #pragma unroll
        for (int k = 0; k < 7; ++k) {
            const float g = Gc[k];
            a0 += g * vA[1 + k]; a1 += g * vA[2 + k];
            e0 += g * vB[1 + k]; e1 += g * vB[2 + k];
        }
        uint4 o;
        o.x = cvtpk(a0.x, a0.y);
        o.y = cvtpk(e0.x, e0.y);
        o.z = cvtpk(a1.x, a1.y);
        o.w = cvtpk(e1.x, e1.y);
        *(uint4*)&F[obase + (size_t)(h0 + r) * WDIM + w0] = o;
    };

    auto wstore = [&](int hp, int by) {
        const size_t obase = ((size_t)z * NSL + by) * SLICEPX;
        witem(hp, wr0, ww0, obase);
        if (hact1) witem(hp, wr1, ww1, obase);
    };

    // ---- prologue: rawB[0] <- b0; pf1 <- b0+1 ----
    if (validby(b0))     { issue(pf0, b0); commit(pf0, 0); }
    if (validby(b0 + 1)) issue(pf1, b0 + 1);
    STEP_BARRIER();

    // ---- 8 iterations, ONE barrier each ----
    // iter i (c=b0+i): issue(c+2) [i<6]; H(c): rawB[i&1]->hb[i&1];
    //   Wstore(c-1) from hb[(i+1)&1] [i>=1]; commit(c+1)->rawB[(i+1)&1] [i<7].
    auto iter = [&](auto ICi) {
        constexpr int i = ICi.v;
        const int c = b0 + i;
        if (i < SPB - 2 && validby(c + 2)) issue((i % 2 == 0) ? pf0 : pf1, c + 2);
        if (validby(c)) {
            hitem(i & 1, hr0, hw0);
            if (hact1) hitem(i & 1, hr1, hw1);
        }
        if (i >= 1 && validby(c - 1)) wstore((i + 1) & 1, c - 1);
        if (i < SPB - 1 && validby(c + 1)) commit((i % 2 == 0) ? pf1 : pf0, (i + 1) & 1);
        STEP_BARRIER();
    };
    iter(IC<0>{}); iter(IC<1>{}); iter(IC<2>{}); iter(IC<3>{});
    iter(IC<4>{}); iter(IC<5>{}); iter(IC<6>{}); iter(IC<7>{});

    // epilogue: W-store last slice from hb[(SPB-1)&1] (= hb[1])
    if (validby(b0 + SPB - 1)) wstore((SPB - 1) & 1, b0 + SPB - 1);

    // ---- per-block partial (no atomics) ----
    #pragma unroll
    for (int off = 32; off > 0; off >>= 1) {
        l1n += __shfl_down(l1n, off, 64);
        l1d += __shfl_down(l1d, off, 64);
    }
    const int wave = t >> 6, lane = t & 63;
    if (lane == 0) { red[wave][0] = l1n; red[wave][1] = l1d; }
    __syncthreads();
    if (t == 0) {
        float n = 0.f, dn = 0.f;
        #pragma unroll
        for (int i2 = 0; i2 < NTH / 64; ++i2) { n += red[i2][0]; dn += red[i2][1]; }
        const int bidx = (z * gridDim.y + blockIdx.y) * gridDim.x + blockIdx.x;
        pl1[bidx] = (float2){n, dn};
    }
}

// ===================== Kernel B: D-blur + SSIM (pure register streamer) =====
__global__ __launch_bounds__(512, 4)
void nq_ssim(const uint2* __restrict__ F, float* __restrict__ pssim)
{
    constexpr float Gc[7] = G7INIT;
    constexpr float C1f = 4.0e-4f;   // (0.01*2)^2
    constexpr float C2f = 3.6e-3f;   // (0.03*2)^2
    __shared__ float red[8];

    const int t = threadIdx.x;
    const int p = blockIdx.x * 512 + t;              // 0..36863
    const int gd0 = blockIdx.y * 20;                 // first output d of chunk
    const size_t fb = (size_t)blockIdx.z * NSL * SLICEPX;

    float ssum = 0.f;
    f32x2 wM[7], wE[7];                              // D-window, static slots

    auto loadF = [&](int ds) -> uint2 {
        const int di = gd0 - 3 + ds;
        if ((unsigned)di < (unsigned)DDIM)
            return F[fb + (size_t)(di + 3) * SLICEPX + p];
        return (uint2){0u, 0u};                      // zero-pad
    };

    uint2 nf = loadF(0);

    auto step = [&](auto PPc, int it) {
        constexpr int PP = PPc.v;
        const int ds = it * 7 + PP;                  // 0..27 (26,27 pads)
        if (ds < 26) {
            const uint2 cur = nf;
            if (ds + 1 < 26) nf = loadF(ds + 1);     // prefetch next
            wM[PP] = (f32x2){__uint_as_float(cur.x << 16),
                             __uint_as_float(cur.x & 0xffff0000u)};
            wE[PP] = (f32x2){__uint_as_float(cur.y << 16),
                             __uint_as_float(cur.y & 0xffff0000u)};
            if (ds >= 6) {
                f32x2 mu = {0.f, 0.f}, e2 = {0.f, 0.f};
                #pragma unroll
                for (int k = 0; k < 7; ++k) {
                    const int s = (PP + 1 + k) % 7;  // compile-time per unroll
                    const float g = Gc[k];
                    mu += g * wM[s]; e2 += g * wE[s];
                }
                const float P = mu.x * mu.x, Q = mu.y * mu.y;
                const float u_ = 0.5f * (P + Q);
                const float v_ = 0.5f * (P - Q);
                const float a2 = 0.5f * (e2.x + e2.y);
                const float b2 = 0.5f * (e2.x - e2.y);
                const float num = (v_ + C1f) * (b2 - v_ + C2f);
                const float den = (u_ + C1f) * (a2 - u_ + C2f);
                ssum += num * rcp_fast(den);
            }
        }
    };

    for (int it = 0; it < 4; ++it) {
        step(IC<0>{}, it); step(IC<1>{}, it); step(IC<2>{}, it);
        step(IC<3>{}, it); step(IC<4>{}, it); step(IC<5>{}, it);
        step(IC<6>{}, it);
    }

    #pragma unroll
    for (int off = 32; off > 0; off >>= 1) ssum += __shfl_down(ssum, off, 64);
    const int wave = t >> 6, lane = t & 63;
    if (lane == 0) red[wave] = ssum;
    __syncthreads();
    if (t == 0) {
        float s = 0.f;
        #pragma unroll
        for (int i = 0; i < 8; ++i) s += red[i];
        pssim[(blockIdx.z * gridDim.y + blockIdx.y) * gridDim.x + blockIdx.x] = s;
    }
}

// ===================== final reduce of partials =====================
__global__ void nq_reduce(const float* __restrict__ pssim, int nss,
                          const float2* __restrict__ pl1, int nl1,
                          const float* __restrict__ vq, float* __restrict__ out)
{
    __shared__ float red[4][3];
    const int t = threadIdx.x;                       // 256 threads
    float s = 0.f, n = 0.f, dn = 0.f;
    for (int i = t; i < nss; i += 256) s += pssim[i];
    for (int i = t; i < nl1; i += 256) { const float2 v = pl1[i]; n += v.x; dn += v.y; }
    #pragma unroll
    for (int off = 32; off > 0; off >>= 1) {
        s  += __shfl_down(s,  off, 64);
        n  += __shfl_down(n,  off, 64);
        dn += __shfl_down(dn, off, 64);
    }
    const int wave = t >> 6, lane = t & 63;
    if (lane == 0) { red[wave][0] = s; red[wave][1] = n; red[wave][2] = dn; }
    __syncthreads();
    if (t == 0) {
        float S = 0.f, N = 0.f, DN = 0.f;
        #pragma unroll
        for (int i = 0; i < 4; ++i) { S += red[i][0]; N += red[i][1]; DN += red[i][2]; }
        out[0] = N / DN + 0.5f * (1.0f - S / (float)NTOT) + vq[0];
    }
}

// ===================== Fallback: R5 monolithic kernel (proven 172 us) =======
#define FTH 8
#define FTW 64
#define FSEG 20
#define FNSEG (DDIM / FSEG)
#define FNS  (FSEG + 6)
#define FNTH 512
#define FRHH (FTH + 6)
#define FRWW 70
#define FNRAW (FRHH * FRWW)
#define FHBSTR 72

__global__ __launch_bounds__(FNTH, 4)
void nq_mono(const float* __restrict__ X, const float* __restrict__ Y,
             float* __restrict__ acc)
{
    constexpr float Gc[7] = G7INIT;
    constexpr float C1f = 4.0e-4f;
    constexpr float C2f = 3.6e-3f;

    __shared__ __align__(16) f32x2 raw[2][FNRAW];
    __shared__ __align__(16) f32x2 hbA[2][FTH][FHBSTR];
    __shared__ __align__(16) f32x2 hbB[2][FTH][FHBSTR];
    __shared__ float red[FNTH / 64][3];

    const int wt  = blockIdx.x;
    const int ht  = blockIdx.y;
    const int b   = blockIdx.z >> 3;
    const int seg = blockIdx.z & 7;
    const int h0 = ht * FTH, w0 = wt * FTW;
    const int dbase = seg * FSEG;
    const long long bbase = (long long)b * (DDIM * HDIM * WDIM);
    const int t = threadIdx.x;

    int goff[2]; bool ok[2], inter[2];
    #pragma unroll
    for (int i = 0; i < 2; ++i) {
        const int idx = t + i * FNTH;
        const int hh = idx / FRWW, ww = idx - hh * FRWW;
        const int h = h0 + hh - 3, w = w0 + ww - 3;
        bool o_ = ((unsigned)h < HDIM) && ((unsigned)w < WDIM);
        bool in_ = ((unsigned)(hh - 3) < FTH) && ((unsigned)(ww - 3) < FTW);
        if (i == 1 && idx >= FNRAW) { o_ = false; in_ = false; }
        ok[i] = o_; inter[i] = in_;
        goff[i] = h * WDIM + w;
    }
    const bool has1 = (t + FNTH) < FNRAW;

    const int q0r = t / FRWW,          q0w = t - q0r * FRWW;
    const int q1r = (t + FNTH) / FRWW, q1w = (t + FNTH) - q1r * FRWW;
    const bool q1on = t < (FTH * FRWW - FNTH);

    const int p4r = t >> 6;
    const int p4c = t & 63;

    float ssum = 0.f, l1n = 0.f, l1d = 0.f;
    f32x2 wA[7], wB[7];
    float pfs[2], pfd[2];

    auto loadslice = [&](int s) {
        const int d_g = dbase - 3 + s;
        const bool dok = (unsigned)d_g < (unsigned)DDIM;
        const long long sb = bbase + (long long)d_g * (HDIM * WDIM);
        const bool l1on = (s >= 3) && (s <= FSEG + 2);
        #pragma unroll
        for (int i = 0; i < 2; ++i) {
            const bool l = dok && ok[i];
            const float xv = l ? X[sb + goff[i]] : 0.f;
            const float yv = l ? Y[sb + goff[i]] : 0.f;
            if (l1on && inter[i]) {
                const float wgt = (yv > -0.9f) ? 5.f : 1.f;
                l1n += wgt * fabsf(xv - yv);
                l1d += wgt;
            }
            pfs[i] = xv + yv;
            pfd[i] = xv - yv;
        }
    };

    auto commit = [&](int s) {
        const int rb = s & 1;
        raw[rb][t] = (f32x2){pfs[0], pfd[0]};
        if (has1) raw[rb][t + FNTH] = (f32x2){pfs[1], pfd[1]};
    };

    auto p2item = [&](int rb, int r, int w) {
        f32x2 aA = {0.f, 0.f}, aB = {0.f, 0.f};
        #pragma unroll
        for (int k = 0; k < 7; ++k) {
            const f32x2 p = raw[rb][(r + k) * FRWW + w];
            const float g = Gc[k];
            aA += g * p;
            aB += (g * p) * p;
        }
        hbA[rb][r][w] = aA;
        hbB[rb][r][w] = aB;
    };

    auto phase = [&](auto PPc, int it) {
        constexpr int PP = PPc.v;
        constexpr int SLOT = (PP + 6) % 7;
        const int ps = it * 7 + PP;
        const int par = ps & 1;

        if (ps <= FNS - 2) commit(ps + 1);
        if (ps <= FNS - 3) loadslice(ps + 2);

        if (ps <= FNS - 1) {
            p2item(par, q0r, q0w);
            if (q1on) p2item(par, q1r, q1w);
        }
        if (ps >= 1 && ps <= FNS) {
            const int hp = par ^ 1;
            f32x2 a = {0.f, 0.f}, bv = {0.f, 0.f};
            #pragma unroll
            for (int k = 0; k < 7; ++k) {
                const float g = Gc[k];
                a  += g * hbA[hp][p4r][p4c + k];
                bv += g * hbB[hp][p4r][p4c + k];
            }
            wA[SLOT] = a; wB[SLOT] = bv;
            if (ps >= 7) {
                f32x2 mu = {0.f, 0.f}, e2 = {0.f, 0.f};
                #pragma unroll
                for (int k = 0; k < 7; ++k) {
                    const int s = (PP + k) % 7;
                    const float g = Gc[k];
                    mu += g * wA[s]; e2 += g * wB[s];
                }
                const float P = mu.x * mu.x, Q = mu.y * mu.y;
                const float u  = 0.5f * (P + Q);
                const float v_ = 0.5f * (P - Q);
                const float a2 = 0.5f * (e2.x + e2.y);
                const float b2 = 0.5f * (e2.x - e2.y);
                const float num = (v_ + C1f) * (b2 - v_ + C2f);
                const float den = (u  + C1f) * (a2 - u  + C2f);
                ssum += num * rcp_fast(den);
            }
        }
        __syncthreads();
    };

    loadslice(0);
    commit(0);
    loadslice(1);
    __syncthreads();

    for (int it = 0; it < 4; ++it) {
        phase(IC<0>{}, it); phase(IC<1>{}, it); phase(IC<2>{}, it);
        phase(IC<3>{}, it); phase(IC<4>{}, it); phase(IC<5>{}, it);
        phase(IC<6>{}, it);
    }

    #pragma unroll
    for (int off = 32; off > 0; off >>= 1) {
        ssum += __shfl_down(ssum, off, 64);
        l1n  += __shfl_down(l1n,  off, 64);
        l1d  += __shfl_down(l1d,  off, 64);
    }
    const int wave = t >> 6, lane = t & 63;
    if (lane == 0) { red[wave][0] = ssum; red[wave][1] = l1n; red[wave][2] = l1d; }
    __syncthreads();
    if (t == 0) {
        float s = 0.f, n = 0.f, dn = 0.f;
        #pragma unroll
        for (int i = 0; i < FNTH / 64; ++i) {
            s += red[i][0]; n += red[i][1]; dn += red[i][2];
        }
        atomicAdd(&acc[0], s);
        atomicAdd(&acc[1], n);
        atomicAdd(&acc[2], dn);
    }
}

__global__ void nq_final_acc(const float* __restrict__ acc,
                             const float* __restrict__ vq,
                             float* __restrict__ out)
{
    const float ssim_mean = acc[0] / (float)NTOT;
    out[0] = acc[1] / acc[2] + 0.5f * (1.0f - ssim_mean) + vq[0];
}

extern "C" void kernel_launch(void* const* d_in, const int* in_sizes, int n_in,
                              void* d_out, int out_size, void* d_ws, size_t ws_size,
                              hipStream_t stream)
{
    const float* X  = (const float*)d_in[0];  // recon
    const float* Y  = (const float*)d_in[1];  // target
    const float* vq = (const float*)d_in[2];  // scalar
    float* out = (float*)d_out;

    const size_t needFull = 256 + (size_t)BDIM * NSL * SLICEPX * 8;  // ~187 MiB

    if (ws_size >= needFull) {
        uint2* F = (uint2*)((char*)d_ws + 256);
        // partials live in F's provably-unused tail (batch 3, slices 163..165)
        char* tail = (char*)d_ws + 256 + (size_t)(3 * NSL + 163) * SLICEPX * 8;
        float*  pssim = (float*)tail;                   // 2304 floats
        float2* pl1   = (float2*)(tail + 16384);        // 2016 float2

        nq_fields<<<dim3(24, 21, 4), NTH, 0, stream>>>(X, Y, F, pl1);
        nq_ssim  <<<dim3(72, 8, 4),  512, 0, stream>>>(F, pssim);
        nq_reduce<<<1, 256, 0, stream>>>(pssim, 2304, pl1, 2016, vq, out);
    } else {
        float* acc = (float*)d_ws;
        hipMemsetAsync(acc, 0, 16, stream);
        nq_mono<<<dim3(WDIM / FTW, HDIM / FTH, BDIM * FNSEG), FNTH, 0, stream>>>(X, Y, acc);
        nq_final_acc<<<1, 1, 0, stream>>>(acc, vq, out);
    }
}

// Round 21
// 132.514 us; speedup vs baseline: 1.0634x; 1.0634x over previous
//
#include <hip/hip_runtime.h>
#include <math.h>

typedef __attribute__((ext_vector_type(2))) float f32x2;
typedef __attribute__((ext_vector_type(4))) float f32x4;

// Problem dims (fixed): (B=4, 1, D=160, H=192, W=192) f32
#define BDIM 4
#define DDIM 160
#define HDIM 192
#define WDIM 192
#define NTOT (BDIM * DDIM * HDIM * WDIM)
#define SLICEPX (HDIM * WDIM)          // 36864

template<int N> struct IC { static constexpr int v = N; };

__device__ __forceinline__ float rcp_fast(float x) {
#if __has_builtin(__builtin_amdgcn_rcpf)
    return __builtin_amdgcn_rcpf(x);
#else
    return 1.0f / x;
#endif
}

// packed pair: {lo16: bf16(lo), hi16: bf16(hi)} in ONE instruction
__device__ __forceinline__ unsigned cvtpk(float lo, float hi) {
    unsigned r;
    asm("v_cvt_pk_bf16_f32 %0, %1, %2" : "=v"(r) : "v"(lo), "v"(hi));
    return r;
}

// unpack bf16 pair -> f32x2 {lo, hi}
__device__ __forceinline__ f32x2 unpk(unsigned u) {
    return (f32x2){__uint_as_float(u << 16), __uint_as_float(u & 0xffff0000u)};
}

#define G7INIT { 0.03663285f, 0.11128076f, 0.21674532f, 0.27068215f, \
                 0.21674532f, 0.11128076f, 0.03663285f }

// LDS-visibility-only barrier: prefetch global loads stay in flight across it.
#define STEP_BARRIER() do {                                   \
    asm volatile("s_waitcnt lgkmcnt(0)" ::: "memory");        \
    __builtin_amdgcn_s_barrier();                             \
} while (0)

// ===================== Kernel A: per-slice H+W blur -> bf16 fields ==========
// s/d basis fields: HW(s), HW(d), HW(s^2), HW(d^2) packed 4 x bf16 (uint2).
// ONE barrier per slice: {issue(c+2) | H(c) | Wstore(c-1) | commit(c+1)}.
// raw bf16-packed parity dbuf (21.5 KB) + hb parity f32 (51.2 KB) = 72.8 KB
// -> 2 blocks/CU (PROVEN regime; (512,4), VGPR 56, zero spill).
// SPB=4 is the bracketed optimum (SPB=8 regressed: fewer barrier domains).
#define ATH 8
#define ARH 14               // ATH + 6
#define HBW 200              // 4 zero-pad cols each side (16B-aligned b128 reads)
#define NSL 166              // buffer slices per batch (by = d+3, d=-3..162)
#define SPB 4                // slices per block
#define NTH 512

struct PFBuf { f32x4 x0, y0, x1, y1; };

__global__ __launch_bounds__(NTH, 4)
void nq_fields(const float* __restrict__ X, const float* __restrict__ Y,
               uint2* __restrict__ F, float2* __restrict__ pl1)
{
    constexpr float Gc[7] = G7INIT;
    __shared__ __align__(16) unsigned rawB[2][ARH][WDIM];  // 21,504 B bf16(s,d)
    __shared__ __align__(16) f32x2 hA[2][ATH][HBW];        // 25,600 B (Hs,Hd)
    __shared__ __align__(16) f32x2 hB[2][ATH][HBW];        // 25,600 B (Hs2,Hd2)
    __shared__ float red[NTH / 64][2];

    const int t = threadIdx.x;
    const int strip = blockIdx.x;                    // 0..23
    const int z = blockIdx.z;                        // batch 0..3
    const int h0 = strip * ATH;
    const int b0 = blockIdx.y * SPB;                 // even (SPB=4)

    // ---- load invariants: two float4 items (672 = 512 + 160) ----
    const int r0 = t / 48, c0 = (t % 48) * 4;
    const int h0r0 = h0 + r0 - 3;
    const bool okh0 = (unsigned)h0r0 < (unsigned)HDIM;
    const bool int0 = (r0 >= 3) && (r0 < 11);
    const int off0 = h0r0 * WDIM + c0;
    const int lof0 = r0 * WDIM + c0;                 // raw flat index

    const bool act1 = t < 160;
    const int i4b = 512 + t;
    const int r1 = i4b / 48, c1 = (i4b % 48) * 4;
    const int h0r1 = h0 + r1 - 3;
    const bool okh1 = act1 && ((unsigned)h0r1 < (unsigned)HDIM);
    const bool int1 = act1 && (r1 >= 3) && (r1 < 11);
    const int off1 = h0r1 * WDIM + c1;
    const int lof1 = r1 * WDIM + c1;

    // ---- H-blur invariants: 2-px items (768 = 512 + 256) ----
    const int hr0 = t / 96,         hw0 = (t % 96) * 2;
    const int hr1 = (t + 512) / 96, hw1 = ((t + 512) % 96) * 2;
    const bool hact1 = t < 256;

    // ---- W-phase invariants: 2-px items (768 = 512 + 256) ----
    const int wr0 = t / 96,         ww0 = (t % 96) * 2;
    const int wr1 = (t + 512) / 96, ww1 = ((t + 512) % 96) * 2;

    // zero pad cols (both parities)
    if (t < 128) {
        const int pp = t >> 6, r = (t >> 3) & 7, c8 = t & 7;
        const int col = (c8 < 4) ? c8 : (192 + c8);
        hA[pp][r][col] = (f32x2){0.f, 0.f};
        hB[pp][r][col] = (f32x2){0.f, 0.f};
    }

    float l1n = 0.f, l1d = 0.f;
    PFBuf pf0, pf1;

    auto validby = [&](int by) { return (by >= 3) && (by < 163); };

    auto issue = [&](PFBuf& p, int by) {             // global loads -> regs
        const int d = by - 3;
        const size_t sbase = ((size_t)z * DDIM + d) * SLICEPX;
        const f32x4 zz = {0.f, 0.f, 0.f, 0.f};
        p.x0 = okh0 ? *(const f32x4*)(X + sbase + off0) : zz;
        p.y0 = okh0 ? *(const f32x4*)(Y + sbase + off0) : zz;
        p.x1 = okh1 ? *(const f32x4*)(X + sbase + off1) : zz;
        p.y1 = okh1 ? *(const f32x4*)(Y + sbase + off1) : zz;
    };

    auto commit = [&](PFBuf& p, int par) {           // L1 + pack s/d -> rawB[par]
        if (int0) {
            #pragma unroll
            for (int j = 0; j < 4; ++j) {
                const float x = p.x0[j], y = p.y0[j];
                const float wgt = (y > -0.9f) ? 5.f : 1.f;
                l1n += wgt * fabsf(x - y);
                l1d += wgt;
            }
        }
        if (int1) {
            #pragma unroll
            for (int j = 0; j < 4; ++j) {
                const float x = p.x1[j], y = p.y1[j];
                const float wgt = (y > -0.9f) ? 5.f : 1.f;
                l1n += wgt * fabsf(x - y);
                l1d += wgt;
            }
        }
        {
            uint4 u;
            u.x = cvtpk(p.x0.x + p.y0.x, p.x0.x - p.y0.x);
            u.y = cvtpk(p.x0.y + p.y0.y, p.x0.y - p.y0.y);
            u.z = cvtpk(p.x0.z + p.y0.z, p.x0.z - p.y0.z);
            u.w = cvtpk(p.x0.w + p.y0.w, p.x0.w - p.y0.w);
            *(uint4*)(&rawB[par][0][0] + lof0) = u;
        }
        if (act1) {
            uint4 u;
            u.x = cvtpk(p.x1.x + p.y1.x, p.x1.x - p.y1.x);
            u.y = cvtpk(p.x1.y + p.y1.y, p.x1.y - p.y1.y);
            u.z = cvtpk(p.x1.z + p.y1.z, p.x1.z - p.y1.z);
            u.w = cvtpk(p.x1.w + p.y1.w, p.x1.w - p.y1.w);
            *(uint4*)(&rawB[par][0][0] + lof1) = u;
        }
    };

    auto hitem = [&](int par, int r, int w0) {       // 2-px H-blur from bf16 raw
        f32x2 aA0 = {0.f, 0.f}, aA1 = {0.f, 0.f};
        f32x2 aB0 = {0.f, 0.f}, aB1 = {0.f, 0.f};
        #pragma unroll
        for (int k = 0; k < 7; ++k) {
            const uint2 u = *(const uint2*)(&rawB[par][r + k][w0]);
            const f32x2 p0 = unpk(u.x);
            const f32x2 p1 = unpk(u.y);
            const float g = Gc[k];
            aA0 += g * p0; aB0 += (g * p0) * p0;
            aA1 += g * p1; aB1 += (g * p1) * p1;
        }
        *(f32x4*)(&hA[par][r][4 + w0]) = (f32x4){aA0.x, aA0.y, aA1.x, aA1.y};
        *(f32x4*)(&hB[par][r][4 + w0]) = (f32x4){aB0.x, aB0.y, aB1.x, aB1.y};
    };

    auto witem = [&](int hp, int r, int w0, size_t obase) {
        f32x2 vA[10], vB[10];
        #pragma unroll
        for (int j = 0; j < 5; ++j) {
            const f32x4 qa = *(const f32x4*)(&hA[hp][r][w0 + 2 * j]);
            vA[2 * j] = (f32x2){qa.x, qa.y}; vA[2 * j + 1] = (f32x2){qa.z, qa.w};
            const f32x4 qb = *(const f32x4*)(&hB[hp][r][w0 + 2 * j]);
            vB[2 * j] = (f32x2){qb.x, qb.y}; vB[2 * j + 1] = (f32x2){qb.z, qb.w};
        }
        f32x2 a0 = {0.f, 0.f}, a1 = {0.f, 0.f};
        f32x2 e0 = {0.f, 0.f}, e1 = {0.f, 0.f};
        #pragma unroll
        for (int k = 0; k < 7; ++k) {
            const float g = Gc[k];
            a0 += g * vA[1 + k]; a1 += g * vA[2 + k];
            e0 += g * vB[1 + k]; e1 += g * vB[2 + k];
        }
        uint4 o;
        o.x = cvtpk(a0.x, a0.y);
        o.y = cvtpk(e0.x, e0.y);
        o.z = cvtpk(a1.x, a1.y);
        o.w = cvtpk(e1.x, e1.y);
        *(uint4*)&F[obase + (size_t)(h0 + r) * WDIM + w0] = o;
    };

    auto wstore = [&](int hp, int by) {
        const size_t obase = ((size_t)z * NSL + by) * SLICEPX;
        witem(hp, wr0, ww0, obase);
        if (hact1) witem(hp, wr1, ww1, obase);
    };

    // ---- prologue: rawB[0] <- b0; pf1 <- b0+1 ----
    if (validby(b0))     { issue(pf0, b0); commit(pf0, 0); }
    if (validby(b0 + 1)) issue(pf1, b0 + 1);
    STEP_BARRIER();

    // ---- 4 iterations, ONE barrier each ----
    // iter i (c=b0+i): issue(c+2); H(c): rawB[i&1]->hb[i&1];
    //                  Wstore(c-1) from hb[(i+1)&1]; commit(c+1)->rawB[(i+1)&1].
    auto iter = [&](auto ICi) {
        constexpr int i = ICi.v;
        const int c = b0 + i;
        if (i < 2 && validby(c + 2)) issue((i == 0) ? pf0 : pf1, c + 2);
        if (validby(c)) {
            hitem(i & 1, hr0, hw0);
            if (hact1) hitem(i & 1, hr1, hw1);
        }
        if (i >= 1 && validby(c - 1)) wstore((i + 1) & 1, c - 1);
        if (i < 3 && validby(c + 1)) commit((i % 2 == 0) ? pf1 : pf0, (i + 1) & 1);
        STEP_BARRIER();
    };
    iter(IC<0>{}); iter(IC<1>{}); iter(IC<2>{}); iter(IC<3>{});

    // epilogue: W-store last slice from hb[1] (written by iter 3, barrier done)
    if (validby(b0 + 3)) wstore(1, b0 + 3);

    // ---- per-block partial (no atomics) ----
    #pragma unroll
    for (int off = 32; off > 0; off >>= 1) {
        l1n += __shfl_down(l1n, off, 64);
        l1d += __shfl_down(l1d, off, 64);
    }
    const int wave = t >> 6, lane = t & 63;
    if (lane == 0) { red[wave][0] = l1n; red[wave][1] = l1d; }
    __syncthreads();
    if (t == 0) {
        float n = 0.f, dn = 0.f;
        #pragma unroll
        for (int i2 = 0; i2 < NTH / 64; ++i2) { n += red[i2][0]; dn += red[i2][1]; }
        const int bidx = (z * gridDim.y + blockIdx.y) * gridDim.x + blockIdx.x;
        pl1[bidx] = (float2){n, dn};
    }
}

// ===================== Kernel B: D-blur + SSIM (pure register streamer) =====
__global__ __launch_bounds__(512, 4)
void nq_ssim(const uint2* __restrict__ F, float* __restrict__ pssim)
{
    constexpr float Gc[7] = G7INIT;
    constexpr float C1f = 4.0e-4f;   // (0.01*2)^2
    constexpr float C2f = 3.6e-3f;   // (0.03*2)^2
    __shared__ float red[8];

    const int t = threadIdx.x;
    const int p = blockIdx.x * 512 + t;              // 0..36863
    const int gd0 = blockIdx.y * 20;                 // first output d of chunk
    const size_t fb = (size_t)blockIdx.z * NSL * SLICEPX;

    float ssum = 0.f;
    f32x2 wM[7], wE[7];                              // D-window, static slots

    auto loadF = [&](int ds) -> uint2 {
        const int di = gd0 - 3 + ds;
        if ((unsigned)di < (unsigned)DDIM)
            return F[fb + (size_t)(di + 3) * SLICEPX + p];
        return (uint2){0u, 0u};                      // zero-pad
    };

    uint2 nf = loadF(0);

    auto step = [&](auto PPc, int it) {
        constexpr int PP = PPc.v;
        const int ds = it * 7 + PP;                  // 0..27 (26,27 pads)
        if (ds < 26) {
            const uint2 cur = nf;
            if (ds + 1 < 26) nf = loadF(ds + 1);     // prefetch next
            wM[PP] = (f32x2){__uint_as_float(cur.x << 16),
                             __uint_as_float(cur.x & 0xffff0000u)};
            wE[PP] = (f32x2){__uint_as_float(cur.y << 16),
                             __uint_as_float(cur.y & 0xffff0000u)};
            if (ds >= 6) {
                f32x2 mu = {0.f, 0.f}, e2 = {0.f, 0.f};
                #pragma unroll
                for (int k = 0; k < 7; ++k) {
                    const int s = (PP + 1 + k) % 7;  // compile-time per unroll
                    const float g = Gc[k];
                    mu += g * wM[s]; e2 += g * wE[s];
                }
                const float P = mu.x * mu.x, Q = mu.y * mu.y;
                const float u_ = 0.5f * (P + Q);
                const float v_ = 0.5f * (P - Q);
                const float a2 = 0.5f * (e2.x + e2.y);
                const float b2 = 0.5f * (e2.x - e2.y);
                const float num = (v_ + C1f) * (b2 - v_ + C2f);
                const float den = (u_ + C1f) * (a2 - u_ + C2f);
                ssum += num * rcp_fast(den);
            }
        }
    };

    for (int it = 0; it < 4; ++it) {
        step(IC<0>{}, it); step(IC<1>{}, it); step(IC<2>{}, it);
        step(IC<3>{}, it); step(IC<4>{}, it); step(IC<5>{}, it);
        step(IC<6>{}, it);
    }

    #pragma unroll
    for (int off = 32; off > 0; off >>= 1) ssum += __shfl_down(ssum, off, 64);
    const int wave = t >> 6, lane = t & 63;
    if (lane == 0) red[wave] = ssum;
    __syncthreads();
    if (t == 0) {
        float s = 0.f;
        #pragma unroll
        for (int i = 0; i < 8; ++i) s += red[i];
        pssim[(blockIdx.z * gridDim.y + blockIdx.y) * gridDim.x + blockIdx.x] = s;
    }
}

// ===================== final reduce of partials =====================
__global__ void nq_reduce(const float* __restrict__ pssim, int nss,
                          const float2* __restrict__ pl1, int nl1,
                          const float* __restrict__ vq, float* __restrict__ out)
{
    __shared__ float red[4][3];
    const int t = threadIdx.x;                       // 256 threads
    float s = 0.f, n = 0.f, dn = 0.f;
    for (int i = t; i < nss; i += 256) s += pssim[i];
    for (int i = t; i < nl1; i += 256) { const float2 v = pl1[i]; n += v.x; dn += v.y; }
    #pragma unroll
    for (int off = 32; off > 0; off >>= 1) {
        s  += __shfl_down(s,  off, 64);
        n  += __shfl_down(n,  off, 64);
        dn += __shfl_down(dn, off, 64);
    }
    const int wave = t >> 6, lane = t & 63;
    if (lane == 0) { red[wave][0] = s; red[wave][1] = n; red[wave][2] = dn; }
    __syncthreads();
    if (t == 0) {
        float S = 0.f, N = 0.f, DN = 0.f;
        #pragma unroll
        for (int i = 0; i < 4; ++i) { S += red[i][0]; N += red[i][1]; DN += red[i][2]; }
        out[0] = N / DN + 0.5f * (1.0f - S / (float)NTOT) + vq[0];
    }
}

// ===================== Fallback: R5 monolithic kernel (proven 172 us) =======
#define FTH 8
#define FTW 64
#define FSEG 20
#define FNSEG (DDIM / FSEG)
#define FNS  (FSEG + 6)
#define FNTH 512
#define FRHH (FTH + 6)
#define FRWW 70
#define FNRAW (FRHH * FRWW)
#define FHBSTR 72

__global__ __launch_bounds__(FNTH, 4)
void nq_mono(const float* __restrict__ X, const float* __restrict__ Y,
             float* __restrict__ acc)
{
    constexpr float Gc[7] = G7INIT;
    constexpr float C1f = 4.0e-4f;
    constexpr float C2f = 3.6e-3f;

    __shared__ __align__(16) f32x2 raw[2][FNRAW];
    __shared__ __align__(16) f32x2 hbA[2][FTH][FHBSTR];
    __shared__ __align__(16) f32x2 hbB[2][FTH][FHBSTR];
    __shared__ float red[FNTH / 64][3];

    const int wt  = blockIdx.x;
    const int ht  = blockIdx.y;
    const int b   = blockIdx.z >> 3;
    const int seg = blockIdx.z & 7;
    const int h0 = ht * FTH, w0 = wt * FTW;
    const int dbase = seg * FSEG;
    const long long bbase = (long long)b * (DDIM * HDIM * WDIM);
    const int t = threadIdx.x;

    int goff[2]; bool ok[2], inter[2];
    #pragma unroll
    for (int i = 0; i < 2; ++i) {
        const int idx = t + i * FNTH;
        const int hh = idx / FRWW, ww = idx - hh * FRWW;
        const int h = h0 + hh - 3, w = w0 + ww - 3;
        bool o_ = ((unsigned)h < HDIM) && ((unsigned)w < WDIM);
        bool in_ = ((unsigned)(hh - 3) < FTH) && ((unsigned)(ww - 3) < FTW);
        if (i == 1 && idx >= FNRAW) { o_ = false; in_ = false; }
        ok[i] = o_; inter[i] = in_;
        goff[i] = h * WDIM + w;
    }
    const bool has1 = (t + FNTH) < FNRAW;

    const int q0r = t / FRWW,          q0w = t - q0r * FRWW;
    const int q1r = (t + FNTH) / FRWW, q1w = (t + FNTH) - q1r * FRWW;
    const bool q1on = t < (FTH * FRWW - FNTH);

    const int p4r = t >> 6;
    const int p4c = t & 63;

    float ssum = 0.f, l1n = 0.f, l1d = 0.f;
    f32x2 wA[7], wB[7];
    float pfs[2], pfd[2];

    auto loadslice = [&](int s) {
        const int d_g = dbase - 3 + s;
        const bool dok = (unsigned)d_g < (unsigned)DDIM;
        const long long sb = bbase + (long long)d_g * (HDIM * WDIM);
        const bool l1on = (s >= 3) && (s <= FSEG + 2);
        #pragma unroll
        for (int i = 0; i < 2; ++i) {
            const bool l = dok && ok[i];
            const float xv = l ? X[sb + goff[i]] : 0.f;
            const float yv = l ? Y[sb + goff[i]] : 0.f;
            if (l1on && inter[i]) {
                const float wgt = (yv > -0.9f) ? 5.f : 1.f;
                l1n += wgt * fabsf(xv - yv);
                l1d += wgt;
            }
            pfs[i] = xv + yv;
            pfd[i] = xv - yv;
        }
    };

    auto commit = [&](int s) {
        const int rb = s & 1;
        raw[rb][t] = (f32x2){pfs[0], pfd[0]};
        if (has1) raw[rb][t + FNTH] = (f32x2){pfs[1], pfd[1]};
    };

    auto p2item = [&](int rb, int r, int w) {
        f32x2 aA = {0.f, 0.f}, aB = {0.f, 0.f};
        #pragma unroll
        for (int k = 0; k < 7; ++k) {
            const f32x2 p = raw[rb][(r + k) * FRWW + w];
            const float g = Gc[k];
            aA += g * p;
            aB += (g * p) * p;
        }
        hbA[rb][r][w] = aA;
        hbB[rb][r][w] = aB;
    };

    auto phase = [&](auto PPc, int it) {
        constexpr int PP = PPc.v;
        constexpr int SLOT = (PP + 6) % 7;
        const int ps = it * 7 + PP;
        const int par = ps & 1;

        if (ps <= FNS - 2) commit(ps + 1);
        if (ps <= FNS - 3) loadslice(ps + 2);

        if (ps <= FNS - 1) {
            p2item(par, q0r, q0w);
            if (q1on) p2item(par, q1r, q1w);
        }
        if (ps >= 1 && ps <= FNS) {
            const int hp = par ^ 1;
            f32x2 a = {0.f, 0.f}, bv = {0.f, 0.f};
            #pragma unroll
            for (int k = 0; k < 7; ++k) {
                const float g = Gc[k];
                a  += g * hbA[hp][p4r][p4c + k];
                bv += g * hbB[hp][p4r][p4c + k];
            }
            wA[SLOT] = a; wB[SLOT] = bv;
            if (ps >= 7) {
                f32x2 mu = {0.f, 0.f}, e2 = {0.f, 0.f};
                #pragma unroll
                for (int k = 0; k < 7; ++k) {
                    const int s = (PP + k) % 7;
                    const float g = Gc[k];
                    mu += g * wA[s]; e2 += g * wB[s];
                }
                const float P = mu.x * mu.x, Q = mu.y * mu.y;
                const float u  = 0.5f * (P + Q);
                const float v_ = 0.5f * (P - Q);
                const float a2 = 0.5f * (e2.x + e2.y);
                const float b2 = 0.5f * (e2.x - e2.y);
                const float num = (v_ + C1f) * (b2 - v_ + C2f);
                const float den = (u  + C1f) * (a2 - u  + C2f);
                ssum += num * rcp_fast(den);
            }
        }
        __syncthreads();
    };

    loadslice(0);
    commit(0);
    loadslice(1);
    __syncthreads();

    for (int it = 0; it < 4; ++it) {
        phase(IC<0>{}, it); phase(IC<1>{}, it); phase(IC<2>{}, it);
        phase(IC<3>{}, it); phase(IC<4>{}, it); phase(IC<5>{}, it);
        phase(IC<6>{}, it);
    }

    #pragma unroll
    for (int off = 32; off > 0; off >>= 1) {
        ssum += __shfl_down(ssum, off, 64);
        l1n  += __shfl_down(l1n,  off, 64);
        l1d  += __shfl_down(l1d,  off, 64);
    }
    const int wave = t >> 6, lane = t & 63;
    if (lane == 0) { red[wave][0] = ssum; red[wave][1] = l1n; red[wave][2] = l1d; }
    __syncthreads();
    if (t == 0) {
        float s = 0.f, n = 0.f, dn = 0.f;
        #pragma unroll
        for (int i = 0; i < FNTH / 64; ++i) {
            s += red[i][0]; n += red[i][1]; dn += red[i][2];
        }
        atomicAdd(&acc[0], s);
        atomicAdd(&acc[1], n);
        atomicAdd(&acc[2], dn);
    }
}

__global__ void nq_final_acc(const float* __restrict__ acc,
                             const float* __restrict__ vq,
                             float* __restrict__ out)
{
    const float ssim_mean = acc[0] / (float)NTOT;
    out[0] = acc[1] / acc[2] + 0.5f * (1.0f - ssim_mean) + vq[0];
}

extern "C" void kernel_launch(void* const* d_in, const int* in_sizes, int n_in,
                              void* d_out, int out_size, void* d_ws, size_t ws_size,
                              hipStream_t stream)
{
    const float* X  = (const float*)d_in[0];  // recon
    const float* Y  = (const float*)d_in[1];  // target
    const float* vq = (const float*)d_in[2];  // scalar
    float* out = (float*)d_out;

    const size_t needFull = 256 + (size_t)BDIM * NSL * SLICEPX * 8;  // ~187 MiB

    if (ws_size >= needFull) {
        uint2* F = (uint2*)((char*)d_ws + 256);
        // partials live in F's provably-unused tail (batch 3, slices 163..165)
        char* tail = (char*)d_ws + 256 + (size_t)(3 * NSL + 163) * SLICEPX * 8;
        float*  pssim = (float*)tail;                   // 2304 floats
        float2* pl1   = (float2*)(tail + 16384);        // 4032 float2

        nq_fields<<<dim3(24, 42, 4), NTH, 0, stream>>>(X, Y, F, pl1);
        nq_ssim  <<<dim3(72, 8, 4),  512, 0, stream>>>(F, pssim);
        nq_reduce<<<1, 256, 0, stream>>>(pssim, 2304, pl1, 4032, vq, out);
    } else {
        float* acc = (float*)d_ws;
        hipMemsetAsync(acc, 0, 16, stream);
        nq_mono<<<dim3(WDIM / FTW, HDIM / FTH, BDIM * FNSEG), FNTH, 0, stream>>>(X, Y, acc);
        nq_final_acc<<<1, 1, 0, stream>>>(acc, vq, out);
    }
}